// Round 7
// baseline (510.527 us; speedup 1.0000x reference)
//
#include <hip/hip_runtime.h>
#include <hip/hip_cooperative_groups.h>

namespace cg = cooperative_groups;

// ---------------- types & helpers ----------------
typedef __attribute__((ext_vector_type(8))) short bf16x8;
typedef __attribute__((ext_vector_type(4))) float f32x4;
typedef __attribute__((ext_vector_type(4))) unsigned uint32x4;

#define MFMA32(a, b, c) __builtin_amdgcn_mfma_f32_16x16x32_bf16((a), (b), (c), 0, 0, 0)

__device__ __forceinline__ unsigned short f2bf(float f) {
  unsigned u = __builtin_bit_cast(unsigned, f);
  u += 0x7fffu + ((u >> 16) & 1u);   // RNE
  return (unsigned short)(u >> 16);
}
__device__ __forceinline__ unsigned pack2(float a, float b) {
  return (unsigned)f2bf(a) | ((unsigned)f2bf(b) << 16);
}
// truncating pack of two fp32 -> bf16x2 in ONE v_perm_b32 (bias cancels in
// softmax normalization; values are non-negative O(1))
__device__ __forceinline__ unsigned pack2t(float lo, float hi) {
  return __builtin_amdgcn_perm(__builtin_bit_cast(unsigned, hi),
                               __builtin_bit_cast(unsigned, lo), 0x07060302u);
}
// async global->LDS, 16B per lane; LDS dest = wave-uniform base + lane*16
__device__ __forceinline__ void gl_lds16(const unsigned short* g, unsigned short* l) {
  __builtin_amdgcn_global_load_lds(
      (const __attribute__((address_space(1))) unsigned int*)(g),
      (__attribute__((address_space(3))) unsigned int*)(l), 16, 0, 0);
}

// Problem constants: B=2, T=2048, C=1024, H=16, D=64, 3C=3072, M=B*T=4096
// Q is stored pre-scaled by 0.125 * log2(e) so attention uses exp2 directly.
#define QSCALE 0.18033688011112042f

// ---------------- fused prep kernel (EXACT R0) ----------------
__global__ __launch_bounds__(256) void prep_kernel(
    const float* __restrict__ x, const float* __restrict__ Wqkv,
    const float* __restrict__ Wo, unsigned short* __restrict__ xb,
    unsigned short* __restrict__ wqt, unsigned short* __restrict__ wot) {
  __shared__ unsigned short Tl[64][72];
  const int bid = blockIdx.x, tid = threadIdx.x;
  if (bid < 2048) {
    int i = (bid * 256 + tid) * 8;
    float4 a = *(const float4*)(x + i);
    float4 b = *(const float4*)(x + i + 4);
    uint4 w;
    w.x = pack2(a.x, a.y); w.y = pack2(a.z, a.w);
    w.z = pack2(b.x, b.y); w.w = pack2(b.z, b.w);
    *(uint4*)(xb + i) = w;
  } else {
    const float* src;
    unsigned short* dst;
    int N, kt, nt;
    if (bid < 2816) {
      int r = bid - 2048;
      src = Wqkv; dst = wqt; N = 3072;
      nt = (r % 48) * 64; kt = (r / 48) * 64;
    } else {
      int r = bid - 2816;
      src = Wo; dst = wot; N = 1024;
      nt = (r & 15) * 64; kt = (r >> 4) * 64;
    }
    const int rr = tid >> 2, cs = (tid & 3) * 16;
    const float* sp = src + (kt + rr) * N + nt + cs;
    uint4 w0, w1;
    {
      float4 a = *(const float4*)(sp), b = *(const float4*)(sp + 4);
      float4 c = *(const float4*)(sp + 8), d = *(const float4*)(sp + 12);
      w0.x = pack2(a.x, a.y); w0.y = pack2(a.z, a.w);
      w0.z = pack2(b.x, b.y); w0.w = pack2(b.z, b.w);
      w1.x = pack2(c.x, c.y); w1.y = pack2(c.z, c.w);
      w1.z = pack2(d.x, d.y); w1.w = pack2(d.z, d.w);
    }
    *(uint4*)(&Tl[rr][cs]) = w0;
    *(uint4*)(&Tl[rr][cs + 8]) = w1;
    __syncthreads();
    unsigned short tmp[16];
#pragma unroll
    for (int i = 0; i < 16; i++) tmp[i] = Tl[cs + i][rr];
    unsigned short* dp = dst + (nt + rr) * 1024 + kt + cs;
    *(uint4*)(dp) = *(const uint4*)(&tmp[0]);
    *(uint4*)(dp + 8) = *(const uint4*)(&tmp[8]);
  }
}

// ---------------- kernel 1: QKV GEMM + RoPE + scatter (EXACT R0) ----------------
// 64x128 tile, grid 24x64, 6 blocks/CU equilibrium (R1-R3: every pipeline
// variant costing LDS/occupancy is net-negative on this kernel).
__global__ __launch_bounds__(256, 6) void qkv_rope_kernel(
    const unsigned short* __restrict__ xb, const unsigned short* __restrict__ wt,
    unsigned short* __restrict__ qws, unsigned short* __restrict__ kws,
    unsigned short* __restrict__ vws) {
  __shared__ unsigned short Al[2 * 64 * 32];   // 8KB
  __shared__ unsigned short Bl[2 * 128 * 32];  // 16KB

  const int tid = threadIdx.x;
  const int lane = tid & 63, wid = tid >> 6;
  const int quad = lane >> 4, col = lane & 15;
  const int wm = (wid >> 1) * 32, wn = (wid & 1) * 64;
  const int n0 = blockIdx.x * 128, m0 = blockIdx.y * 64;

  f32x4 acc[2][4] = {};
  const int srA = wid * 16 + (lane >> 2);
  const int srB = wid * 32 + (lane >> 2);
  const int gseg = ((lane & 3) ^ ((lane >> 3) & 3)) * 8;
  const int fsg = (quad ^ ((col >> 1) & 3)) * 8;

  for (int k0 = 0; k0 < 1024; k0 += 64) {
#pragma unroll
    for (int c = 0; c < 2; c++) {
      const int kc = k0 + c * 32;
      gl_lds16(xb + (m0 + srA) * 1024 + kc + gseg, Al + c * 2048 + (wid * 16) * 32);
      gl_lds16(wt + (n0 + srB) * 1024 + kc + gseg, Bl + c * 4096 + (wid * 32) * 32);
      gl_lds16(wt + (n0 + srB + 16) * 1024 + kc + gseg,
               Bl + c * 4096 + (wid * 32 + 16) * 32);
    }
    __syncthreads();

#pragma unroll
    for (int c = 0; c < 2; c++) {
      bf16x8 af[2], bfr[4];
#pragma unroll
      for (int i = 0; i < 2; i++)
        af[i] = *(const bf16x8*)(&Al[c * 2048 + (wm + i * 16 + col) * 32 + fsg]);
#pragma unroll
      for (int j = 0; j < 4; j++)
        bfr[j] = *(const bf16x8*)(&Bl[c * 4096 + (wn + j * 16 + col) * 32 + fsg]);
#pragma unroll
      for (int i = 0; i < 2; i++)
#pragma unroll
        for (int j = 0; j < 4; j++)
          acc[i][j] = MFMA32(af[i], bfr[j], acc[i][j]);
    }
    __syncthreads();
  }

#pragma unroll
  for (int i = 0; i < 2; i++) {
#pragma unroll
    for (int j = 0; j < 4; j++) {
      const int nbase = n0 + wn + j * 16;   // wave-uniform
      const int region = nbase >> 10;       // 0=q, 1=k, 2=v
#pragma unroll
      for (int r = 0; r < 4; r++) {
        int m = m0 + wm + i * 16 + quad * 4 + r;
        int n = nbase + col;
        float val = acc[i][j][r];
        int nn = n & 1023, h = nn >> 6, d = nn & 63, b = m >> 11, t = m & 2047;
        if (region < 2) {
          float other = __shfl_xor(val, 1);  // partner dim (d^1)
          float invf = __expf(-(float)(d >> 1) * 0.28782313662425572f);  // ln(1e4)/32
          float ang = (float)t * invf;
          float sn, cs;
          __sincosf(ang, &sn, &cs);
          float rot = (d & 1) ? other : -other;
          val = fmaf(val, cs, rot * sn);
        }
        int bh = (b << 4) + h;
        if (region == 0) {
          qws[(bh * 2048 + t) * 64 + d] = f2bf(val * QSCALE);
        } else if (region == 1) {
          kws[(bh * 2048 + t) * 64 + d] = f2bf(val);
        } else {
          int tl = t & 31, g = t >> 5;
          int qd = (tl & 15) >> 2;
          int jj = (tl & 3) + ((tl & 16) ? 4 : 0);
          int tp = g * 32 + qd * 8 + jj;
          vws[(bh * 64 + d) * 2048 + tp] = f2bf(val);
        }
      }
    }
  }
}

// ---------------- kernel 2: FUSED attention + out-proj (cooperative) ----------------
// Phase 1 = EXACT R5 staged attn (47.2us measured: MfmaUtil 13.6, VALUBusy 56,
// conflicts 0; R6 proved staging is load-bearing). Phase 2 = out-proj retiled
// to 64x64 (1024 tiles, 1/block, balanced; gains TLP vs old 2-blocks/CU).
// Grid sync between phases removes one ~12us dispatch boundary (measured:
// non-kernel gap approx 13us per dispatch across R4/R5/R6). 1024 blocks at
// 4/CU (LDS 32KB of 160, waves 16/32, VGPR<=128) -> co-residency assured.
// __threadfence both sides of sync: aws crosses XCDs (per-XCD L2 non-coherent).
__global__ __launch_bounds__(256, 4) void attn_proj_kernel(
    const unsigned short* __restrict__ qws, const unsigned short* __restrict__ kws,
    const unsigned short* __restrict__ vws, unsigned short* __restrict__ aws,
    const unsigned short* __restrict__ wot, const float* __restrict__ bo,
    float* __restrict__ out) {
  __shared__ unsigned short SMEM[16384];  // 32KB, reused by both phases

  const int tid = threadIdx.x;
  const int lane = tid & 63, wid = tid >> 6;
  const int quad = lane >> 4, col = lane & 15;
  const int bid = blockIdx.x;

  // ===== phase 1: causal flash attention =====
  {
    const int bh = bid & 31;  // fast dim -> bh%8 XCD locality as before
    const unsigned short* qb = qws + bh * (2048 * 64);
    const unsigned short* kb = kws + bh * (2048 * 64);
    const unsigned short* vb = vws + bh * (64 * 2048);
    const int b = bh >> 4, h = bh & 15;

    const int sro = wid * 16 + (lane >> 3);
    const int sgs = ((lane & 7) ^ ((lane >> 3) & 7)) * 8;
    const int sA = (quad ^ (col & 7)) * 8;

    const int q0blk = (31 - (bid >> 5)) * 64;  // heavy-first
    const int qt = q0blk + wid * 16;
    const int qi = qt + col;
    const int qi_max = qt + 15;
    const int kend = q0blk + 64;

    bf16x8 qf0 = *(const bf16x8*)(qb + (qt + col) * 64 + quad * 8);
    bf16x8 qf1 = *(const bf16x8*)(qb + (qt + col) * 64 + 32 + quad * 8);

    f32x4 o[4] = {};
    float lsum = 0.f;

    for (int k0 = 0; k0 < kend; k0 += 128) {
      const int nsub = (kend - k0 > 64) ? 2 : 1;  // block-uniform
      for (int u = 0; u < nsub; u++) {
        const int kb0 = k0 + u * 64;
        unsigned short* KlU = SMEM + u * 4096;
        unsigned short* VlU = SMEM + 8192 + u * 4096;
        gl_lds16(kb + (kb0 + sro) * 64 + sgs, KlU + (wid * 16) * 64);
        gl_lds16(kb + (kb0 + sro + 8) * 64 + sgs, KlU + (wid * 16 + 8) * 64);
        gl_lds16(vb + sro * 2048 + kb0 + sgs, VlU + (wid * 16) * 64);
        gl_lds16(vb + (sro + 8) * 2048 + kb0 + sgs, VlU + (wid * 16 + 8) * 64);
      }
      __syncthreads();

      for (int u = 0; u < nsub; u++) {
        const int kb0 = k0 + u * 64;
        if (kb0 > qi_max) break;  // wave-uniform: rest fully masked
        const unsigned short* KlU = SMEM + u * 4096;
        const unsigned short* VlU = SMEM + 8192 + u * 4096;
        const int smax = min(4, ((qi_max - kb0) >> 4) + 1);  // wave-uniform
        const bool diag = (kb0 + 64 > qt);                   // wave-uniform
        float p[16];
#pragma unroll
        for (int s = 0; s < 4; s++) {
          if (s < smax) {
            bf16x8 kfa = *(const bf16x8*)(KlU + (s * 16 + col) * 64 + sA);
            bf16x8 kfb = *(const bf16x8*)(KlU + (s * 16 + col) * 64 + (sA ^ 32));
            f32x4 z = {0.f, 0.f, 0.f, 0.f};
            __builtin_amdgcn_s_setprio(1);
            z = MFMA32(kfa, qf0, z);
            z = MFMA32(kfb, qf1, z);
            __builtin_amdgcn_s_setprio(0);
            if (diag) {
#pragma unroll
              for (int r = 0; r < 4; r++)
                if (kb0 + s * 16 + quad * 4 + r > qi) z[r] = -1e30f;
            }
#pragma unroll
            for (int r = 0; r < 4; r++) {
              float e = exp2f(z[r]);
              p[s * 4 + r] = e;
              lsum += e;
            }
          } else {
#pragma unroll
            for (int r = 0; r < 4; r++) p[s * 4 + r] = 0.f;
          }
        }
        uint32x4 u0;
        u0[0] = pack2t(p[0], p[1]);   u0[1] = pack2t(p[2], p[3]);
        u0[2] = pack2t(p[4], p[5]);   u0[3] = pack2t(p[6], p[7]);
        bf16x8 pf0 = __builtin_bit_cast(bf16x8, u0);
        __builtin_amdgcn_s_setprio(1);
#pragma unroll
        for (int dt = 0; dt < 4; dt++) {
          bf16x8 vfa = *(const bf16x8*)(VlU + (dt * 16 + col) * 64 + sA);
          o[dt] = MFMA32(vfa, pf0, o[dt]);
        }
        __builtin_amdgcn_s_setprio(0);
        if (smax > 2) {
          uint32x4 u1;
          u1[0] = pack2t(p[8], p[9]);   u1[1] = pack2t(p[10], p[11]);
          u1[2] = pack2t(p[12], p[13]); u1[3] = pack2t(p[14], p[15]);
          bf16x8 pf1 = __builtin_bit_cast(bf16x8, u1);
          __builtin_amdgcn_s_setprio(1);
#pragma unroll
          for (int dt = 0; dt < 4; dt++) {
            bf16x8 vfb = *(const bf16x8*)(VlU + (dt * 16 + col) * 64 + (sA ^ 32));
            o[dt] = MFMA32(vfb, pf1, o[dt]);
          }
          __builtin_amdgcn_s_setprio(0);
        }
      }
      __syncthreads();
    }

    lsum += __shfl_xor(lsum, 16);
    lsum += __shfl_xor(lsum, 32);
    float inv = 1.0f / lsum;
#pragma unroll
    for (int dt = 0; dt < 4; dt++)
#pragma unroll
      for (int r = 0; r < 4; r++) {
        int d = dt * 16 + quad * 4 + r;
        aws[(b * 2048 + qt + col) * 1024 + h * 64 + d] = f2bf(o[dt][r] * inv);
      }
  }

  __threadfence();          // release aws stores device-wide (cross-XCD)
  cg::this_grid().sync();   // all attention outputs complete
  __threadfence();          // acquire side

  // ===== phase 2: out-proj 64x64 tiles (1024 tiles, 1 per block) =====
  {
    unsigned short* Al = SMEM;          // [2][64][32] 8KB
    unsigned short* Bl = SMEM + 4096;   // [2][64][32] 8KB
    const int n0 = (bid & 15) * 64, m0 = (bid >> 4) * 64;
    f32x4 acc[4] = {};
    const int sr = wid * 16 + (lane >> 2);
    const int gseg = ((lane & 3) ^ ((lane >> 3) & 3)) * 8;
    const int fsg = (quad ^ ((col >> 1) & 3)) * 8;

    for (int k0 = 0; k0 < 1024; k0 += 64) {
#pragma unroll
      for (int c = 0; c < 2; c++) {
        const int kc = k0 + c * 32;
        gl_lds16(aws + (m0 + sr) * 1024 + kc + gseg, Al + c * 2048 + (wid * 16) * 32);
        gl_lds16(wot + (n0 + sr) * 1024 + kc + gseg, Bl + c * 2048 + (wid * 16) * 32);
      }
      __syncthreads();
#pragma unroll
      for (int c = 0; c < 2; c++) {
        bf16x8 af = *(const bf16x8*)(Al + c * 2048 + (wid * 16 + col) * 32 + fsg);
        bf16x8 bfr[4];
#pragma unroll
        for (int j = 0; j < 4; j++)
          bfr[j] = *(const bf16x8*)(Bl + c * 2048 + (j * 16 + col) * 32 + fsg);
#pragma unroll
        for (int j = 0; j < 4; j++) acc[j] = MFMA32(af, bfr[j], acc[j]);
      }
      __syncthreads();
    }
#pragma unroll
    for (int j = 0; j < 4; j++)
#pragma unroll
      for (int r = 0; r < 4; r++) {
        int m = m0 + wid * 16 + quad * 4 + r;
        int n = n0 + j * 16 + col;
        out[m * 1024 + n] = acc[j][r] + bo[n];
      }
  }
}

// ---------------- fallback standalone kernels (if coop launch unavailable) ----------------
__global__ __launch_bounds__(256, 4) void attn_kernel(
    const unsigned short* __restrict__ qws, const unsigned short* __restrict__ kws,
    const unsigned short* __restrict__ vws, unsigned short* __restrict__ aws) {
  __shared__ unsigned short Kl[2][64 * 64];
  __shared__ unsigned short Vl[2][64 * 64];

  const int tid = threadIdx.x;
  const int lane = tid & 63, wid = tid >> 6;
  const int quad = lane >> 4, col = lane & 15;
  const int bh = blockIdx.x;
  const unsigned short* qb = qws + bh * (2048 * 64);
  const unsigned short* kb = kws + bh * (2048 * 64);
  const unsigned short* vb = vws + bh * (64 * 2048);
  const int b = bh >> 4, h = bh & 15;

  const int sro = wid * 16 + (lane >> 3);
  const int sgs = ((lane & 7) ^ ((lane >> 3) & 7)) * 8;
  const int sA = (quad ^ (col & 7)) * 8;

  const int q0blk = (31 - (int)blockIdx.y) * 64;
  const int qt = q0blk + wid * 16;
  const int qi = qt + col;
  const int qi_max = qt + 15;
  const int kend = q0blk + 64;

  bf16x8 qf0 = *(const bf16x8*)(qb + (qt + col) * 64 + quad * 8);
  bf16x8 qf1 = *(const bf16x8*)(qb + (qt + col) * 64 + 32 + quad * 8);

  f32x4 o[4] = {};
  float lsum = 0.f;

  for (int k0 = 0; k0 < kend; k0 += 128) {
    const int nsub = (kend - k0 > 64) ? 2 : 1;
    for (int u = 0; u < nsub; u++) {
      const int kb0 = k0 + u * 64;
      gl_lds16(kb + (kb0 + sro) * 64 + sgs, Kl[u] + (wid * 16) * 64);
      gl_lds16(kb + (kb0 + sro + 8) * 64 + sgs, Kl[u] + (wid * 16 + 8) * 64);
      gl_lds16(vb + sro * 2048 + kb0 + sgs, Vl[u] + (wid * 16) * 64);
      gl_lds16(vb + (sro + 8) * 2048 + kb0 + sgs, Vl[u] + (wid * 16 + 8) * 64);
    }
    __syncthreads();

    for (int u = 0; u < nsub; u++) {
      const int kb0 = k0 + u * 64;
      if (kb0 > qi_max) break;
      const int smax = min(4, ((qi_max - kb0) >> 4) + 1);
      const bool diag = (kb0 + 64 > qt);
      float p[16];
#pragma unroll
      for (int s = 0; s < 4; s++) {
        if (s < smax) {
          bf16x8 kfa = *(const bf16x8*)(&Kl[u][(s * 16 + col) * 64 + sA]);
          bf16x8 kfb = *(const bf16x8*)(&Kl[u][(s * 16 + col) * 64 + (sA ^ 32)]);
          f32x4 z = {0.f, 0.f, 0.f, 0.f};
          z = MFMA32(kfa, qf0, z);
          z = MFMA32(kfb, qf1, z);
          if (diag) {
#pragma unroll
            for (int r = 0; r < 4; r++)
              if (kb0 + s * 16 + quad * 4 + r > qi) z[r] = -1e30f;
          }
#pragma unroll
          for (int r = 0; r < 4; r++) {
            float e = exp2f(z[r]);
            p[s * 4 + r] = e;
            lsum += e;
          }
        } else {
#pragma unroll
          for (int r = 0; r < 4; r++) p[s * 4 + r] = 0.f;
        }
      }
      uint32x4 u0;
      u0[0] = pack2t(p[0], p[1]);   u0[1] = pack2t(p[2], p[3]);
      u0[2] = pack2t(p[4], p[5]);   u0[3] = pack2t(p[6], p[7]);
      bf16x8 pf0 = __builtin_bit_cast(bf16x8, u0);
#pragma unroll
      for (int dt = 0; dt < 4; dt++) {
        bf16x8 vfa = *(const bf16x8*)(&Vl[u][(dt * 16 + col) * 64 + sA]);
        o[dt] = MFMA32(vfa, pf0, o[dt]);
      }
      if (smax > 2) {
        uint32x4 u1;
        u1[0] = pack2t(p[8], p[9]);   u1[1] = pack2t(p[10], p[11]);
        u1[2] = pack2t(p[12], p[13]); u1[3] = pack2t(p[14], p[15]);
        bf16x8 pf1 = __builtin_bit_cast(bf16x8, u1);
#pragma unroll
        for (int dt = 0; dt < 4; dt++) {
          bf16x8 vfb = *(const bf16x8*)(&Vl[u][(dt * 16 + col) * 64 + (sA ^ 32)]);
          o[dt] = MFMA32(vfb, pf1, o[dt]);
        }
      }
    }
    __syncthreads();
  }

  lsum += __shfl_xor(lsum, 16);
  lsum += __shfl_xor(lsum, 32);
  float inv = 1.0f / lsum;
#pragma unroll
  for (int dt = 0; dt < 4; dt++)
#pragma unroll
    for (int r = 0; r < 4; r++) {
      int d = dt * 16 + quad * 4 + r;
      aws[(b * 2048 + qt + col) * 1024 + h * 64 + d] = f2bf(o[dt][r] * inv);
    }
}

__global__ __launch_bounds__(256) void out_proj_kernel(
    const unsigned short* __restrict__ attn, const unsigned short* __restrict__ wot,
    const float* __restrict__ bo, float* __restrict__ out) {
  __shared__ unsigned short Al[2 * 64 * 32];
  __shared__ unsigned short Bl[2 * 128 * 32];

  const int tid = threadIdx.x;
  const int lane = tid & 63, wid = tid >> 6;
  const int quad = lane >> 4, col = lane & 15;
  const int wm = (wid >> 1) * 32, wn = (wid & 1) * 64;
  const int n0 = blockIdx.x * 128, m0 = blockIdx.y * 64;

  f32x4 acc[2][4] = {};
  const int sr = lane >> 2;
  const int gseg = ((lane & 3) ^ ((lane >> 3) & 3)) * 8;
  const int fsg = (quad ^ ((col >> 1) & 3)) * 8;

  for (int k0 = 0; k0 < 1024; k0 += 64) {
#pragma unroll
    for (int c = 0; c < 2; c++) {
      const int kc = k0 + c * 32;
      gl_lds16(attn + (m0 + wid * 16 + sr) * 1024 + kc + gseg,
               Al + c * 2048 + (wid * 16) * 32);
      gl_lds16(wot + (n0 + wid * 32 + sr) * 1024 + kc + gseg,
               Bl + c * 4096 + (wid * 32) * 32);
      gl_lds16(wot + (n0 + wid * 32 + 16 + sr) * 1024 + kc + gseg,
               Bl + c * 4096 + (wid * 32 + 16) * 32);
    }
    __syncthreads();

#pragma unroll
    for (int c = 0; c < 2; c++) {
      bf16x8 af[2], bfr[4];
#pragma unroll
      for (int i = 0; i < 2; i++)
        af[i] = *(const bf16x8*)(&Al[c * 2048 + (wm + i * 16 + col) * 32 + fsg]);
#pragma unroll
      for (int j = 0; j < 4; j++)
        bfr[j] = *(const bf16x8*)(&Bl[c * 4096 + (wn + j * 16 + col) * 32 + fsg]);
#pragma unroll
      for (int i = 0; i < 2; i++)
#pragma unroll
        for (int j = 0; j < 4; j++)
          acc[i][j] = MFMA32(af[i], bfr[j], acc[i][j]);
    }
    __syncthreads();
  }

#pragma unroll
  for (int i = 0; i < 2; i++)
#pragma unroll
    for (int j = 0; j < 4; j++)
#pragma unroll
      for (int r = 0; r < 4; r++) {
        int m = m0 + wm + i * 16 + quad * 4 + r;
        int n = n0 + wn + j * 16 + col;
        out[m * 1024 + n] = acc[i][j][r] + bo[n];
      }
}

// ---------------- launch ----------------
extern "C" void kernel_launch(void* const* d_in, const int* in_sizes, int n_in,
                              void* d_out, int out_size, void* d_ws, size_t ws_size,
                              hipStream_t stream) {
  const float* x = (const float*)d_in[0];
  const float* Wqkv = (const float*)d_in[1];
  const float* Wo = (const float*)d_in[2];
  const float* bo = (const float*)d_in[3];
  float* out = (float*)d_out;

  unsigned short* qws = (unsigned short*)d_ws;   // [32][2048][64]      8.4 MB
  unsigned short* kws = qws + 4194304;           // [32][2048][64]      8.4 MB
  unsigned short* vws = kws + 4194304;           // [32][64][2048]      8.4 MB
  unsigned short* xb  = vws + 4194304;           // [4096][1024] (dead after qkv)
  unsigned short* aws = xb;                      //   reused: attn out [4096][1024]
  unsigned short* wqt = xb + 4194304;            // [3072][1024]        6.3 MB
  unsigned short* wot = wqt + 3145728;           // [1024][1024]        2.1 MB

  prep_kernel<<<3072, 256, 0, stream>>>(x, Wqkv, Wo, xb, wqt, wot);
  qkv_rope_kernel<<<dim3(24, 64), 256, 0, stream>>>(xb, wqt, qws, kws, vws);

  {
    void* cargs[] = {(void*)&qws, (void*)&kws, (void*)&vws, (void*)&aws,
                     (void*)&wot, (void*)&bo, (void*)&out};
    hipError_t cerr = hipLaunchCooperativeKernel(
        (const void*)attn_proj_kernel, dim3(1024), dim3(256), cargs, 0, stream);
    if (cerr != hipSuccess) {
      (void)hipGetLastError();  // clear error, fall back to split dispatches
      attn_kernel<<<dim3(32, 32), 256, 0, stream>>>(qws, kws, vws, aws);
      out_proj_kernel<<<dim3(8, 64), 256, 0, stream>>>(aws, wot, bo, out);
    }
  }
}

// Round 8
// 201.783 us; speedup vs baseline: 2.5301x; 2.5301x over previous
//
#include <hip/hip_runtime.h>

// ---------------- types & helpers ----------------
typedef __attribute__((ext_vector_type(8))) short bf16x8;
typedef __attribute__((ext_vector_type(4))) float f32x4;
typedef __attribute__((ext_vector_type(4))) unsigned uint32x4;

#define MFMA32(a, b, c) __builtin_amdgcn_mfma_f32_16x16x32_bf16((a), (b), (c), 0, 0, 0)

__device__ __forceinline__ unsigned short f2bf(float f) {
  unsigned u = __builtin_bit_cast(unsigned, f);
  u += 0x7fffu + ((u >> 16) & 1u);   // RNE
  return (unsigned short)(u >> 16);
}
__device__ __forceinline__ unsigned pack2(float a, float b) {
  return (unsigned)f2bf(a) | ((unsigned)f2bf(b) << 16);
}
// truncating pack of two fp32 -> bf16x2 in ONE v_perm_b32 (bias cancels in
// softmax normalization; values are non-negative O(1))
__device__ __forceinline__ unsigned pack2t(float lo, float hi) {
  return __builtin_amdgcn_perm(__builtin_bit_cast(unsigned, hi),
                               __builtin_bit_cast(unsigned, lo), 0x07060302u);
}
// async global->LDS, 16B per lane; LDS dest = wave-uniform base + lane*16
__device__ __forceinline__ void gl_lds16(const unsigned short* g, unsigned short* l) {
  __builtin_amdgcn_global_load_lds(
      (const __attribute__((address_space(1))) unsigned int*)(g),
      (__attribute__((address_space(3))) unsigned int*)(l), 16, 0, 0);
}

// Problem constants: B=2, T=2048, C=1024, H=16, D=64, 3C=3072, M=B*T=4096
// Q is stored pre-scaled by 0.125 * log2(e) so attention uses exp2 directly.
#define QSCALE 0.18033688011112042f

// ---------------- fused prep kernel (EXACT R0) ----------------
__global__ __launch_bounds__(256) void prep_kernel(
    const float* __restrict__ x, const float* __restrict__ Wqkv,
    const float* __restrict__ Wo, unsigned short* __restrict__ xb,
    unsigned short* __restrict__ wqt, unsigned short* __restrict__ wot) {
  __shared__ unsigned short Tl[64][72];
  const int bid = blockIdx.x, tid = threadIdx.x;
  if (bid < 2048) {
    int i = (bid * 256 + tid) * 8;
    float4 a = *(const float4*)(x + i);
    float4 b = *(const float4*)(x + i + 4);
    uint4 w;
    w.x = pack2(a.x, a.y); w.y = pack2(a.z, a.w);
    w.z = pack2(b.x, b.y); w.w = pack2(b.z, b.w);
    *(uint4*)(xb + i) = w;
  } else {
    const float* src;
    unsigned short* dst;
    int N, kt, nt;
    if (bid < 2816) {
      int r = bid - 2048;
      src = Wqkv; dst = wqt; N = 3072;
      nt = (r % 48) * 64; kt = (r / 48) * 64;
    } else {
      int r = bid - 2816;
      src = Wo; dst = wot; N = 1024;
      nt = (r & 15) * 64; kt = (r >> 4) * 64;
    }
    const int rr = tid >> 2, cs = (tid & 3) * 16;
    const float* sp = src + (kt + rr) * N + nt + cs;
    uint4 w0, w1;
    {
      float4 a = *(const float4*)(sp), b = *(const float4*)(sp + 4);
      float4 c = *(const float4*)(sp + 8), d = *(const float4*)(sp + 12);
      w0.x = pack2(a.x, a.y); w0.y = pack2(a.z, a.w);
      w0.z = pack2(b.x, b.y); w0.w = pack2(b.z, b.w);
      w1.x = pack2(c.x, c.y); w1.y = pack2(c.z, c.w);
      w1.z = pack2(d.x, d.y); w1.w = pack2(d.z, d.w);
    }
    *(uint4*)(&Tl[rr][cs]) = w0;
    *(uint4*)(&Tl[rr][cs + 8]) = w1;
    __syncthreads();
    unsigned short tmp[16];
#pragma unroll
    for (int i = 0; i < 16; i++) tmp[i] = Tl[cs + i][rr];
    unsigned short* dp = dst + (nt + rr) * 1024 + kt + cs;
    *(uint4*)(dp) = *(const uint4*)(&tmp[0]);
    *(uint4*)(dp + 8) = *(const uint4*)(&tmp[8]);
  }
}

// ---------------- kernel 1: QKV GEMM + RoPE + scatter (EXACT R0) ----------------
// 64x128 tile, grid 24x64, 6 blocks/CU equilibrium (R1-R3: every pipeline
// variant costing LDS/occupancy is net-negative on this kernel).
__global__ __launch_bounds__(256, 6) void qkv_rope_kernel(
    const unsigned short* __restrict__ xb, const unsigned short* __restrict__ wt,
    unsigned short* __restrict__ qws, unsigned short* __restrict__ kws,
    unsigned short* __restrict__ vws) {
  __shared__ unsigned short Al[2 * 64 * 32];   // 8KB
  __shared__ unsigned short Bl[2 * 128 * 32];  // 16KB

  const int tid = threadIdx.x;
  const int lane = tid & 63, wid = tid >> 6;
  const int quad = lane >> 4, col = lane & 15;
  const int wm = (wid >> 1) * 32, wn = (wid & 1) * 64;
  const int n0 = blockIdx.x * 128, m0 = blockIdx.y * 64;

  f32x4 acc[2][4] = {};
  const int srA = wid * 16 + (lane >> 2);
  const int srB = wid * 32 + (lane >> 2);
  const int gseg = ((lane & 3) ^ ((lane >> 3) & 3)) * 8;
  const int fsg = (quad ^ ((col >> 1) & 3)) * 8;

  for (int k0 = 0; k0 < 1024; k0 += 64) {
#pragma unroll
    for (int c = 0; c < 2; c++) {
      const int kc = k0 + c * 32;
      gl_lds16(xb + (m0 + srA) * 1024 + kc + gseg, Al + c * 2048 + (wid * 16) * 32);
      gl_lds16(wt + (n0 + srB) * 1024 + kc + gseg, Bl + c * 4096 + (wid * 32) * 32);
      gl_lds16(wt + (n0 + srB + 16) * 1024 + kc + gseg,
               Bl + c * 4096 + (wid * 32 + 16) * 32);
    }
    __syncthreads();

#pragma unroll
    for (int c = 0; c < 2; c++) {
      bf16x8 af[2], bfr[4];
#pragma unroll
      for (int i = 0; i < 2; i++)
        af[i] = *(const bf16x8*)(&Al[c * 2048 + (wm + i * 16 + col) * 32 + fsg]);
#pragma unroll
      for (int j = 0; j < 4; j++)
        bfr[j] = *(const bf16x8*)(&Bl[c * 4096 + (wn + j * 16 + col) * 32 + fsg]);
#pragma unroll
      for (int i = 0; i < 2; i++)
#pragma unroll
        for (int j = 0; j < 4; j++)
          acc[i][j] = MFMA32(af[i], bfr[j], acc[i][j]);
    }
    __syncthreads();
  }

#pragma unroll
  for (int i = 0; i < 2; i++) {
#pragma unroll
    for (int j = 0; j < 4; j++) {
      const int nbase = n0 + wn + j * 16;   // wave-uniform
      const int region = nbase >> 10;       // 0=q, 1=k, 2=v
#pragma unroll
      for (int r = 0; r < 4; r++) {
        int m = m0 + wm + i * 16 + quad * 4 + r;
        int n = nbase + col;
        float val = acc[i][j][r];
        int nn = n & 1023, h = nn >> 6, d = nn & 63, b = m >> 11, t = m & 2047;
        if (region < 2) {
          float other = __shfl_xor(val, 1);  // partner dim (d^1)
          float invf = __expf(-(float)(d >> 1) * 0.28782313662425572f);  // ln(1e4)/32
          float ang = (float)t * invf;
          float sn, cs;
          __sincosf(ang, &sn, &cs);
          float rot = (d & 1) ? other : -other;
          val = fmaf(val, cs, rot * sn);
        }
        int bh = (b << 4) + h;
        if (region == 0) {
          qws[(bh * 2048 + t) * 64 + d] = f2bf(val * QSCALE);
        } else if (region == 1) {
          kws[(bh * 2048 + t) * 64 + d] = f2bf(val);
        } else {
          int tl = t & 31, g = t >> 5;
          int qd = (tl & 15) >> 2;
          int jj = (tl & 3) + ((tl & 16) ? 4 : 0);
          int tp = g * 32 + qd * 8 + jj;
          vws[(bh * 64 + d) * 2048 + tp] = f2bf(val);
        }
      }
    }
  }
}

// ---------------- kernel 2: causal flash attention, 32 q-rows per wave ----------------
// R5 counters isolated attn's cost: VALU ~26us + LDS-port ~20us (each of 4
// waves reads the IDENTICAL 16KB of K/V fragments per chunk = 4x redundant,
// 1.08GB total), MFMA only ~7us. This round: 128-q slab per block, 32 q/wave
// (two 16-col Q register groups g0/g1). Per chunk a wave reads the same 16
// K/V fragments but runs 2x MFMA -> LDS-read traffic per q HALVED, K/V
// staging per q HALVED (each chunk staged once per 128 q), address/loop VALU
// per q halved. exp/pack VALU is per-score (intrinsic), unchanged.
// Grid 32bh x 16 slabs = 512 blocks (2/CU, 8 waves/CU). p registers reused
// between key-half A (s=0,1 -> PV vfa) and half B (s=2,3 -> PV vfb).
__global__ __launch_bounds__(256, 2) void attn_kernel(
    const unsigned short* __restrict__ qws, const unsigned short* __restrict__ kws,
    const unsigned short* __restrict__ vws, unsigned short* __restrict__ aws) {
  __shared__ unsigned short Kl[2][64 * 64];  // [buf][key][dim] swizzled
  __shared__ unsigned short Vl[2][64 * 64];  // [buf][dim][key-permuted]

  const int tid = threadIdx.x;
  const int lane = tid & 63, wid = tid >> 6;
  const int quad = lane >> 4, col = lane & 15;
  const int bh = blockIdx.x;
  const unsigned short* qb = qws + bh * (2048 * 64);
  const unsigned short* kb = kws + bh * (2048 * 64);
  const unsigned short* vb = vws + bh * (64 * 2048);
  const int b = bh >> 4, h = bh & 15;

  const int sro = wid * 16 + (lane >> 3);                   // + 8 for 2nd slot
  const int sgs = ((lane & 7) ^ ((lane >> 3) & 7)) * 8;     // swizzled seg
  const int sA = (quad ^ (col & 7)) * 8;                    // frag read offset

  const int slab = (15 - (int)blockIdx.y) * 128;  // heavy-first
  const int qt0 = slab + wid * 32;                // g0 rows qt0..qt0+15
  const int qt1 = qt0 + 16;                       // g1 rows qt1..qt1+15
  const int qi0 = qt0 + col, qi1 = qt1 + col;
  const int qimax0 = qt0 + 15, qimax1 = qt1 + 15;
  const int kend = slab + 128;                    // block-uniform

  // Q register groups: lane holds Q[qt+col][chunk*32 + quad*8 + j]
  bf16x8 qf0a = *(const bf16x8*)(qb + (qt0 + col) * 64 + quad * 8);
  bf16x8 qf0b = *(const bf16x8*)(qb + (qt0 + col) * 64 + 32 + quad * 8);
  bf16x8 qf1a = *(const bf16x8*)(qb + (qt1 + col) * 64 + quad * 8);
  bf16x8 qf1b = *(const bf16x8*)(qb + (qt1 + col) * 64 + 32 + quad * 8);

  f32x4 o0[4] = {}, o1[4] = {};
  float ls0 = 0.f, ls1 = 0.f;

  for (int k0 = 0; k0 < kend; k0 += 128) {
#pragma unroll
    for (int u = 0; u < 2; u++) {
      const int kb0 = k0 + u * 64;
      gl_lds16(kb + (kb0 + sro) * 64 + sgs, Kl[u] + (wid * 16) * 64);
      gl_lds16(kb + (kb0 + sro + 8) * 64 + sgs, Kl[u] + (wid * 16 + 8) * 64);
      gl_lds16(vb + sro * 2048 + kb0 + sgs, Vl[u] + (wid * 16) * 64);
      gl_lds16(vb + (sro + 8) * 2048 + kb0 + sgs, Vl[u] + (wid * 16 + 8) * 64);
    }
    __syncthreads();

    for (int u = 0; u < 2; u++) {
      const int kb0 = k0 + u * 64;
      if (kb0 > qimax1) break;  // wave-uniform: rest fully masked for this wave
      int d0 = (qimax0 - kb0) >> 4;
      const int smax0 = min(4, max(0, d0 + 1));            // wave-uniform
      const int smax1 = min(4, ((qimax1 - kb0) >> 4) + 1); // wave-uniform, >=1
      const bool diag0 = (kb0 + 64 > qt0);
      const bool diag1 = (kb0 + 64 > qt1);
      float p0[8], p1[8];

      // ---- key half A: s = 0,1 ----
#pragma unroll
      for (int s = 0; s < 2; s++) {
        bf16x8 kfa = *(const bf16x8*)(&Kl[u][(s * 16 + col) * 64 + sA]);
        bf16x8 kfb = *(const bf16x8*)(&Kl[u][(s * 16 + col) * 64 + (sA ^ 32)]);
        if (s < smax0) {
          f32x4 z = {0.f, 0.f, 0.f, 0.f};
          __builtin_amdgcn_s_setprio(1);
          z = MFMA32(kfa, qf0a, z);
          z = MFMA32(kfb, qf0b, z);
          __builtin_amdgcn_s_setprio(0);
          if (diag0) {
#pragma unroll
            for (int r = 0; r < 4; r++)
              if (kb0 + s * 16 + quad * 4 + r > qi0) z[r] = -1e30f;
          }
#pragma unroll
          for (int r = 0; r < 4; r++) {
            float e = exp2f(z[r]);
            p0[s * 4 + r] = e;
            ls0 += e;
          }
        } else {
#pragma unroll
          for (int r = 0; r < 4; r++) p0[s * 4 + r] = 0.f;
        }
        if (s < smax1) {
          f32x4 z = {0.f, 0.f, 0.f, 0.f};
          __builtin_amdgcn_s_setprio(1);
          z = MFMA32(kfa, qf1a, z);
          z = MFMA32(kfb, qf1b, z);
          __builtin_amdgcn_s_setprio(0);
          if (diag1) {
#pragma unroll
            for (int r = 0; r < 4; r++)
              if (kb0 + s * 16 + quad * 4 + r > qi1) z[r] = -1e30f;
          }
#pragma unroll
          for (int r = 0; r < 4; r++) {
            float e = exp2f(z[r]);
            p1[s * 4 + r] = e;
            ls1 += e;
          }
        } else {
#pragma unroll
          for (int r = 0; r < 4; r++) p1[s * 4 + r] = 0.f;
        }
      }
      {
        uint32x4 w0, w1;
        w0[0] = pack2t(p0[0], p0[1]); w0[1] = pack2t(p0[2], p0[3]);
        w0[2] = pack2t(p0[4], p0[5]); w0[3] = pack2t(p0[6], p0[7]);
        w1[0] = pack2t(p1[0], p1[1]); w1[1] = pack2t(p1[2], p1[3]);
        w1[2] = pack2t(p1[4], p1[5]); w1[3] = pack2t(p1[6], p1[7]);
        bf16x8 pg0 = __builtin_bit_cast(bf16x8, w0);
        bf16x8 pg1 = __builtin_bit_cast(bf16x8, w1);
        __builtin_amdgcn_s_setprio(1);
#pragma unroll
        for (int dt = 0; dt < 4; dt++) {
          bf16x8 vfa = *(const bf16x8*)(&Vl[u][(dt * 16 + col) * 64 + sA]);
          o0[dt] = MFMA32(vfa, pg0, o0[dt]);
          o1[dt] = MFMA32(vfa, pg1, o1[dt]);
        }
        __builtin_amdgcn_s_setprio(0);
      }

      // ---- key half B: s = 2,3 (p arrays reused) ----
      if (smax1 > 2) {
#pragma unroll
        for (int s = 2; s < 4; s++) {
          bf16x8 kfa = *(const bf16x8*)(&Kl[u][(s * 16 + col) * 64 + sA]);
          bf16x8 kfb = *(const bf16x8*)(&Kl[u][(s * 16 + col) * 64 + (sA ^ 32)]);
          if (s < smax0) {
            f32x4 z = {0.f, 0.f, 0.f, 0.f};
            __builtin_amdgcn_s_setprio(1);
            z = MFMA32(kfa, qf0a, z);
            z = MFMA32(kfb, qf0b, z);
            __builtin_amdgcn_s_setprio(0);
            if (diag0) {
#pragma unroll
              for (int r = 0; r < 4; r++)
                if (kb0 + s * 16 + quad * 4 + r > qi0) z[r] = -1e30f;
            }
#pragma unroll
            for (int r = 0; r < 4; r++) {
              float e = exp2f(z[r]);
              p0[(s - 2) * 4 + r] = e;
              ls0 += e;
            }
          } else {
#pragma unroll
            for (int r = 0; r < 4; r++) p0[(s - 2) * 4 + r] = 0.f;
          }
          if (s < smax1) {
            f32x4 z = {0.f, 0.f, 0.f, 0.f};
            __builtin_amdgcn_s_setprio(1);
            z = MFMA32(kfa, qf1a, z);
            z = MFMA32(kfb, qf1b, z);
            __builtin_amdgcn_s_setprio(0);
            if (diag1) {
#pragma unroll
              for (int r = 0; r < 4; r++)
                if (kb0 + s * 16 + quad * 4 + r > qi1) z[r] = -1e30f;
            }
#pragma unroll
            for (int r = 0; r < 4; r++) {
              float e = exp2f(z[r]);
              p1[(s - 2) * 4 + r] = e;
              ls1 += e;
            }
          } else {
#pragma unroll
            for (int r = 0; r < 4; r++) p1[(s - 2) * 4 + r] = 0.f;
          }
        }
        uint32x4 w0, w1;
        w0[0] = pack2t(p0[0], p0[1]); w0[1] = pack2t(p0[2], p0[3]);
        w0[2] = pack2t(p0[4], p0[5]); w0[3] = pack2t(p0[6], p0[7]);
        w1[0] = pack2t(p1[0], p1[1]); w1[1] = pack2t(p1[2], p1[3]);
        w1[2] = pack2t(p1[4], p1[5]); w1[3] = pack2t(p1[6], p1[7]);
        bf16x8 pg0 = __builtin_bit_cast(bf16x8, w0);
        bf16x8 pg1 = __builtin_bit_cast(bf16x8, w1);
        const bool g0b = (smax0 > 2);  // wave-uniform
        __builtin_amdgcn_s_setprio(1);
#pragma unroll
        for (int dt = 0; dt < 4; dt++) {
          bf16x8 vfb = *(const bf16x8*)(&Vl[u][(dt * 16 + col) * 64 + (sA ^ 32)]);
          if (g0b) o0[dt] = MFMA32(vfb, pg0, o0[dt]);
          o1[dt] = MFMA32(vfb, pg1, o1[dt]);
        }
        __builtin_amdgcn_s_setprio(0);
      }
    }
    __syncthreads();
  }

  ls0 += __shfl_xor(ls0, 16);
  ls0 += __shfl_xor(ls0, 32);
  ls1 += __shfl_xor(ls1, 16);
  ls1 += __shfl_xor(ls1, 32);
  float inv0 = 1.0f / ls0;
  float inv1 = 1.0f / ls1;
#pragma unroll
  for (int dt = 0; dt < 4; dt++)
#pragma unroll
    for (int r = 0; r < 4; r++) {
      int d = dt * 16 + quad * 4 + r;
      aws[(b * 2048 + qt0 + col) * 1024 + h * 64 + d] = f2bf(o0[dt][r] * inv0);
      aws[(b * 2048 + qt1 + col) * 1024 + h * 64 + d] = f2bf(o1[dt][r] * inv1);
    }
}

// ---------------- kernel 3: output projection + bias (EXACT R0) ----------------
__global__ __launch_bounds__(256) void out_proj_kernel(
    const unsigned short* __restrict__ attn, const unsigned short* __restrict__ wot,
    const float* __restrict__ bo, float* __restrict__ out) {
  __shared__ unsigned short Al[2 * 64 * 32];
  __shared__ unsigned short Bl[2 * 128 * 32];

  const int tid = threadIdx.x;
  const int lane = tid & 63, wid = tid >> 6;
  const int quad = lane >> 4, col = lane & 15;
  const int wm = (wid >> 1) * 32, wn = (wid & 1) * 64;
  const int n0 = blockIdx.x * 128, m0 = blockIdx.y * 64;

  f32x4 acc[2][4] = {};
  const int sr = lane >> 2;
  const int gseg = ((lane & 3) ^ ((lane >> 3) & 3)) * 8;
  const int fsg = (quad ^ ((col >> 1) & 3)) * 8;

  for (int k0 = 0; k0 < 1024; k0 += 64) {
#pragma unroll
    for (int c = 0; c < 2; c++) {
      const int kc = k0 + c * 32;
      gl_lds16(attn + (m0 + wid * 16 + sr) * 1024 + kc + gseg,
               Al + c * 2048 + (wid * 16) * 32);
      gl_lds16(wot + (n0 + wid * 32 + sr) * 1024 + kc + gseg,
               Bl + c * 4096 + (wid * 32) * 32);
      gl_lds16(wot + (n0 + wid * 32 + 16 + sr) * 1024 + kc + gseg,
               Bl + c * 4096 + (wid * 32 + 16) * 32);
    }
    __syncthreads();

#pragma unroll
    for (int c = 0; c < 2; c++) {
      bf16x8 af[2], bfr[4];
#pragma unroll
      for (int i = 0; i < 2; i++)
        af[i] = *(const bf16x8*)(&Al[c * 2048 + (wm + i * 16 + col) * 32 + fsg]);
#pragma unroll
      for (int j = 0; j < 4; j++)
        bfr[j] = *(const bf16x8*)(&Bl[c * 4096 + (wn + j * 16 + col) * 32 + fsg]);
#pragma unroll
      for (int i = 0; i < 2; i++)
#pragma unroll
        for (int j = 0; j < 4; j++)
          acc[i][j] = MFMA32(af[i], bfr[j], acc[i][j]);
    }
    __syncthreads();
  }

#pragma unroll
  for (int i = 0; i < 2; i++)
#pragma unroll
    for (int j = 0; j < 4; j++)
#pragma unroll
      for (int r = 0; r < 4; r++) {
        int m = m0 + wm + i * 16 + quad * 4 + r;
        int n = n0 + wn + j * 16 + col;
        out[m * 1024 + n] = acc[i][j][r] + bo[n];
      }
}

// ---------------- launch ----------------
extern "C" void kernel_launch(void* const* d_in, const int* in_sizes, int n_in,
                              void* d_out, int out_size, void* d_ws, size_t ws_size,
                              hipStream_t stream) {
  const float* x = (const float*)d_in[0];
  const float* Wqkv = (const float*)d_in[1];
  const float* Wo = (const float*)d_in[2];
  const float* bo = (const float*)d_in[3];
  float* out = (float*)d_out;

  unsigned short* qws = (unsigned short*)d_ws;   // [32][2048][64]      8.4 MB
  unsigned short* kws = qws + 4194304;           // [32][2048][64]      8.4 MB
  unsigned short* vws = kws + 4194304;           // [32][64][2048]      8.4 MB
  unsigned short* xb  = vws + 4194304;           // [4096][1024] (dead after qkv)
  unsigned short* aws = xb;                      //   reused: attn out [4096][1024]
  unsigned short* wqt = xb + 4194304;            // [3072][1024]        6.3 MB
  unsigned short* wot = wqt + 3145728;           // [1024][1024]        2.1 MB

  prep_kernel<<<3072, 256, 0, stream>>>(x, Wqkv, Wo, xb, wqt, wot);
  qkv_rope_kernel<<<dim3(24, 64), 256, 0, stream>>>(xb, wqt, qws, kws, vws);
  attn_kernel<<<dim3(32, 16), 256, 0, stream>>>(qws, kws, vws, aws);
  out_proj_kernel<<<dim3(8, 64), 256, 0, stream>>>(aws, wot, bo, out);
}